// Round 3
// baseline (403.947 us; speedup 1.0000x reference)
//
#include <hip/hip_runtime.h>
#include <stdint.h>

#define HDIM  768
#define VOCAB 30522
#define NNODE 10002      // NEW_ROWS - 2
#define NEDGE 50000
#define NROWS 10004
#define SLOPE 0.2f

// ---------- ws layout (bytes) ----------
constexpr size_t OFF_H     = 0;                               // h (bf16)
constexpr size_t SZ_H      = (size_t)NNODE * HDIM * 2;        // 15,363,072
constexpr size_t OFF_AGG   = OFF_H + SZ_H;                    // agg (f32); featbf (bf16) aliases this
constexpr size_t SZ_AGG    = (size_t)NNODE * HDIM * 4;        // 30,726,144
constexpr size_t SZ_N4     = 40016;                           // 10002*4 padded to 16
constexpr size_t OFF_DENOM = OFF_AGG + SZ_AGG;
constexpr size_t OFF_MENC  = OFF_DENOM + SZ_N4;
constexpr size_t OFF_SSRC  = OFF_MENC + SZ_N4;
constexpr size_t OFF_SDST  = OFF_SSRC + SZ_N4;
constexpr size_t OFF_WT    = OFF_SDST + SZ_N4;                // W^T bf16 (N x K)
constexpr size_t SZ_WT     = (size_t)HDIM * HDIM * 2;         // 1,179,648
constexpr size_t OFF_WAS   = OFF_WT + SZ_WT;                  // f32[768]
constexpr size_t OFF_WAD   = OFF_WAS + HDIM * 4;
constexpr size_t OFF_FO    = OFF_WAD + HDIM * 4;              // feat_out f32
constexpr size_t SZ_FO     = (size_t)NNODE * HDIM * 4;        // 30,726,144
constexpr size_t ZERO_BYTES = SZ_AGG + 2 * SZ_N4;             // agg + denom + menc (contiguous)

// ---------- helpers ----------
__device__ __forceinline__ unsigned short f2bf(float f) {
  unsigned int u = __float_as_uint(f);
  u += 0x7FFFu + ((u >> 16) & 1u);
  return (unsigned short)(u >> 16);
}
__device__ __forceinline__ float bf2f(unsigned short b) {
  return __uint_as_float(((unsigned int)b) << 16);
}

typedef __attribute__((ext_vector_type(8))) short bf16x8;
typedef __attribute__((ext_vector_type(4))) float f32x4;

__device__ __forceinline__ void gl2lds16(const unsigned short* g, unsigned short* l) {
  __builtin_amdgcn_global_load_lds(
      (const __attribute__((address_space(1))) unsigned int*)g,
      (__attribute__((address_space(3))) unsigned int*)l, 16, 0, 0);
}

// ---------- 1. prep: W^T (bf16) + wa vectors (f32) ----------
__global__ __launch_bounds__(256) void k_prep(const float* __restrict__ W,
                                              const float* __restrict__ a_s,
                                              const float* __restrict__ a_d,
                                              unsigned short* __restrict__ wT,
                                              float* __restrict__ wa_s,
                                              float* __restrict__ wa_d) {
  int bid = blockIdx.x, tid = threadIdx.x;
  if (bid < 576) {                       // 24x24 tiles of 32x32 transpose
    __shared__ float tile[32][33];
    int tx0 = (bid % 24) * 32, ty0 = (bid / 24) * 32;
    int cx = tid & 31, cy = tid >> 5;    // cy 0..7
#pragma unroll
    for (int r = 0; r < 4; ++r)
      tile[cy + r * 8][cx] = W[(size_t)(ty0 + cy + r * 8) * HDIM + tx0 + cx];
    __syncthreads();
#pragma unroll
    for (int r = 0; r < 4; ++r)
      wT[(size_t)(tx0 + cy + r * 8) * HDIM + ty0 + cx] = f2bf(tile[cx][cy + r * 8]);
  } else {                               // wa rows: 192 blocks * 4 waves = 768 rows
    int lane = tid & 63, wid = tid >> 6;
    int row = (bid - 576) * 4 + wid;
    float ss = 0.f, sd = 0.f;
    for (int n = lane; n < HDIM; n += 64) {
      float w = W[(size_t)row * HDIM + n];
      ss += w * a_s[n];
      sd += w * a_d[n];
    }
#pragma unroll
    for (int off = 32; off; off >>= 1) {
      ss += __shfl_down(ss, off, 64);
      sd += __shfl_down(sd, off, 64);
    }
    if (lane == 0) { wa_s[row] = ss; wa_d[row] = sd; }
  }
}

// ---------- 2. convert feat (f32) -> featbf (bf16 row-major) ----------
__global__ __launch_bounds__(256) void k_convert(const float* __restrict__ feat,
                                                 unsigned short* __restrict__ featbf) {
  int idx = blockIdx.x * 256 + threadIdx.x;       // float4 index
  if (idx >= NNODE * (HDIM / 4)) return;
  float4 v = ((const float4*)feat)[idx];
  ushort4 o;
  o.x = f2bf(v.x); o.y = f2bf(v.y); o.z = f2bf(v.z); o.w = f2bf(v.w);
  ((ushort4*)featbf)[idx] = o;
}

// ---------- 3. scores: s_src/s_dst = feat . wa ----------
__global__ __launch_bounds__(256) void k_scores(const float* __restrict__ feat,
                                                const float* __restrict__ wa_s,
                                                const float* __restrict__ wa_d,
                                                float* __restrict__ s_s,
                                                float* __restrict__ s_d) {
  int lane = threadIdx.x & 63, wid = threadIdx.x >> 6;
  int r = blockIdx.x * 4 + wid;
  if (r >= NNODE) return;
  const float* f = feat + (size_t)r * HDIM;
  float ss = 0.f, sd = 0.f;
  for (int k = lane; k < HDIM; k += 64) {
    float v = f[k];
    ss += v * wa_s[k];
    sd += v * wa_d[k];
  }
#pragma unroll
  for (int off = 32; off; off >>= 1) {
    ss += __shfl_down(ss, off, 64);
    sd += __shfl_down(sd, off, 64);
  }
  if (lane == 0) { s_s[r] = ss; s_d[r] = sd; }
}

// ---------- 4. GEMM h = feat @ W  (A: M x K bf16, BT: N x K bf16) ----------
__global__ __launch_bounds__(256) void k_gemm(const unsigned short* __restrict__ A,
                                              const unsigned short* __restrict__ BT,
                                              unsigned short* __restrict__ Hout) {
  __shared__ __align__(16) unsigned short As[128 * 32];
  __shared__ __align__(16) unsigned short Bs[128 * 32];
  int tid = threadIdx.x, lane = tid & 63, wid = tid >> 6;
  int m0 = blockIdx.x * 128, n0 = blockIdx.y * 128;
  int wm = wid >> 1, wn = wid & 1;
  int q = lane >> 4, lr = lane & 15;

  f32x4 acc[4][4];
#pragma unroll
  for (int i = 0; i < 4; ++i)
#pragma unroll
    for (int j = 0; j < 4; ++j) acc[i][j] = 0.f;

  for (int kt = 0; kt < 24; ++kt) {
    int k0 = kt * 32;
#pragma unroll
    for (int t = 0; t < 2; ++t) {
      int c = wid * 128 + t * 64 + lane;       // chunk id 0..511
      int row = c >> 2, kk = (c & 3) << 3;
      int grow = m0 + row;                      // clamp M tail (values unused)
      grow = grow <= NNODE - 1 ? grow : NNODE - 1;
      gl2lds16(A + (size_t)grow * HDIM + k0 + kk, As + (size_t)wid * 1024 + t * 512);
      int nrow = n0 + row;                      // N=768 exact, no clamp
      gl2lds16(BT + (size_t)nrow * HDIM + k0 + kk, Bs + (size_t)wid * 1024 + t * 512);
    }
    __syncthreads();
    bf16x8 a[4], b[4];
#pragma unroll
    for (int i = 0; i < 4; ++i)
      a[i] = *(const bf16x8*)(As + (wm * 64 + i * 16 + lr) * 32 + q * 8);
#pragma unroll
    for (int j = 0; j < 4; ++j)
      b[j] = *(const bf16x8*)(Bs + (wn * 64 + j * 16 + lr) * 32 + q * 8);
#pragma unroll
    for (int i = 0; i < 4; ++i)
#pragma unroll
      for (int j = 0; j < 4; ++j)
        acc[i][j] = __builtin_amdgcn_mfma_f32_16x16x32_bf16(a[i], b[j], acc[i][j], 0, 0, 0);
    __syncthreads();
  }
  // epilogue: C/D layout col=lane&15, row=(lane>>4)*4+reg
#pragma unroll
  for (int i = 0; i < 4; ++i) {
    int mbase = m0 + wm * 64 + i * 16 + q * 4;
#pragma unroll
    for (int j = 0; j < 4; ++j) {
      int n = n0 + wn * 64 + j * 16 + lr;
#pragma unroll
      for (int rg = 0; rg < 4; ++rg) {
        int m = mbase + rg;
        if (m < NNODE) Hout[(size_t)m * HDIM + n] = f2bf(acc[i][j][rg]);
      }
    }
  }
}

// ---------- 5. edge max (encoded-uint atomicMax) ----------
__global__ __launch_bounds__(256) void k_edge_max(const int* __restrict__ ei,
                                                  const float* __restrict__ s_s,
                                                  const float* __restrict__ s_d,
                                                  unsigned int* __restrict__ menc) {
  int e = blockIdx.x * 256 + threadIdx.x;
  if (e >= NEDGE) return;
  int src = ei[e], dst = ei[NEDGE + e];
  float v = s_s[src] + s_d[dst];
  v = v > 0.f ? v : SLOPE * v;
  unsigned int b = __float_as_uint(v);
  unsigned int enc = (b & 0x80000000u) ? ~b : (b | 0x80000000u);
  atomicMax(menc + dst, enc);
}

// ---------- 6. edge scatter: denom += ex ; agg += ex * h[src] ----------
__global__ __launch_bounds__(256) void k_edge_scatter(const int* __restrict__ ei,
                                                      const float* __restrict__ s_s,
                                                      const float* __restrict__ s_d,
                                                      const unsigned int* __restrict__ menc,
                                                      const unsigned short* __restrict__ h,
                                                      float* __restrict__ denom,
                                                      float* __restrict__ agg) {
  int e = blockIdx.x;
  int src = ei[e], dst = ei[NEDGE + e];
  float v = s_s[src] + s_d[dst];
  v = v > 0.f ? v : SLOPE * v;
  unsigned int u = menc[dst];
  float m = (u & 0x80000000u) ? __uint_as_float(u & 0x7FFFFFFFu) : __uint_as_float(~u);
  float ex = __expf(v - m);
  if (threadIdx.x == 0) atomicAdd(denom + dst, ex);
  const unsigned short* hr = h + (size_t)src * HDIM;
  float* ar = agg + (size_t)dst * HDIM;
  for (int c = threadIdx.x; c < HDIM; c += 256)
    atomicAdd(ar + c, ex * bf2f(hr[c]));
}

// ---------- 7. finalize: feat_out = feat + agg/(denom+1e-16)  (f32) ----------
__global__ __launch_bounds__(256) void k_finalize(const float* __restrict__ feat,
                                                  const float* __restrict__ agg,
                                                  const float* __restrict__ denom,
                                                  float* __restrict__ fo) {
  int idx = blockIdx.x * 256 + threadIdx.x;       // float4 index
  if (idx >= NNODE * (HDIM / 4)) return;
  int r = idx / (HDIM / 4);
  float inv = 1.f / (denom[r] + 1e-16f);
  float4 a = ((const float4*)agg)[idx];
  float4 fv = ((const float4*)feat)[idx];
  float4 o;
  o.x = fv.x + a.x * inv;
  o.y = fv.y + a.y * inv;
  o.z = fv.z + a.z * inv;
  o.w = fv.w + a.w * inv;
  ((float4*)fo)[idx] = o;
}

// ---------- 8. gather: out[b,s,:]  (f32, 16B chunks) ----------
__global__ __launch_bounds__(256) void k_gather(const int* __restrict__ x,
                                                const float* __restrict__ orig,
                                                const float* __restrict__ nw,
                                                const float* __restrict__ soft,
                                                const float* __restrict__ fo,
                                                uint4* __restrict__ out) {
  int chunk = blockIdx.x * 256 + threadIdx.x;     // 192 chunks/row, 32768 rows
  int row = chunk / 192;
  int c4 = chunk - row * 192;                     // float4 index within row
  int s = row & 511;
  const float* g;
  if (s < 8) {
    g = soft + (size_t)s * HDIM + c4 * 4;
  } else {
    int idx = x[row];
    if (idx < VOCAB) g = orig + (size_t)idx * HDIM + c4 * 4;
    else if (idx < VOCAB + NNODE) g = fo + (size_t)(idx - VOCAB) * HDIM + c4 * 4;
    else g = nw + (size_t)(NROWS - 1) * HDIM + c4 * 4;
  }
  out[chunk] = *(const uint4*)g;
}

// ---------- launch ----------
extern "C" void kernel_launch(void* const* d_in, const int* in_sizes, int n_in,
                              void* d_out, int out_size, void* d_ws, size_t ws_size,
                              hipStream_t stream) {
  const int* x    = (const int*)d_in[0];
  const int* ei   = (const int*)d_in[1];
  const float* og = (const float*)d_in[2];
  const float* nw = (const float*)d_in[3];
  const float* sp = (const float*)d_in[4];
  const float* W  = (const float*)d_in[5];
  const float* as = (const float*)d_in[6];
  const float* ad = (const float*)d_in[7];
  const float* feat = nw + HDIM;                  // new_weight rows 1..10002

  char* ws = (char*)d_ws;
  unsigned short* hbuf  = (unsigned short*)(ws + OFF_H);
  float* agg            = (float*)(ws + OFF_AGG);
  unsigned short* featbf= (unsigned short*)(ws + OFF_AGG);   // alias: dead before memset
  float* denom          = (float*)(ws + OFF_DENOM);
  unsigned int* menc    = (unsigned int*)(ws + OFF_MENC);
  float* s_s            = (float*)(ws + OFF_SSRC);
  float* s_d            = (float*)(ws + OFF_SDST);
  unsigned short* wT    = (unsigned short*)(ws + OFF_WT);
  float* wa_s           = (float*)(ws + OFF_WAS);
  float* wa_d           = (float*)(ws + OFF_WAD);
  float* fo             = (float*)(ws + OFF_FO);

  k_prep<<<768, 256, 0, stream>>>(W, as, ad, wT, wa_s, wa_d);
  k_convert<<<(NNODE * (HDIM / 4) + 255) / 256, 256, 0, stream>>>(feat, featbf);
  k_scores<<<(NNODE + 3) / 4, 256, 0, stream>>>(feat, wa_s, wa_d, s_s, s_d);
  k_gemm<<<dim3(79, 6), 256, 0, stream>>>(featbf, wT, hbuf);
  (void)hipMemsetAsync(agg, 0, ZERO_BYTES, stream);   // zero agg+denom+menc (featbf dead now)
  k_edge_max<<<(NEDGE + 255) / 256, 256, 0, stream>>>(ei, s_s, s_d, menc);
  k_edge_scatter<<<NEDGE, 256, 0, stream>>>(ei, s_s, s_d, menc, hbuf, denom, agg);
  k_finalize<<<(NNODE * (HDIM / 4) + 255) / 256, 256, 0, stream>>>(feat, agg, denom, fo);
  k_gather<<<(32768 * 192) / 256, 256, 0, stream>>>(x, og, nw, sp, fo, (uint4*)d_out);
}

// Round 4
// 298.419 us; speedup vs baseline: 1.3536x; 1.3536x over previous
//
#include <hip/hip_runtime.h>
#include <stdint.h>

#define HDIM  768
#define VOCAB 30522
#define NNODE 10002      // NEW_ROWS - 2
#define NEDGE 50000
#define NROWS 10004
#define SLOPE 0.2f

// ---------- ws layout (bytes) ----------
constexpr size_t SZ_HB     = (size_t)NNODE * HDIM * 2;        // 15,363,072
constexpr size_t SZ_F32    = (size_t)NNODE * HDIM * 4;        // 30,726,144
constexpr size_t OFF_H     = 0;                               // h (bf16)
constexpr size_t OFF_FB    = OFF_H  + SZ_HB;                  // featbf (bf16)
constexpr size_t OFF_FO    = OFF_FB + SZ_HB;                  // feat_out (f32)
constexpr size_t OFF_WT    = OFF_FO + SZ_F32;                 // W^T bf16
constexpr size_t SZ_WT     = (size_t)HDIM * HDIM * 2;
constexpr size_t OFF_WAS   = OFF_WT + SZ_WT;
constexpr size_t OFF_WAD   = OFF_WAS + HDIM * 4;
constexpr size_t OFF_SS    = OFF_WAD + HDIM * 4;              // s_src f32[NNODE]
constexpr size_t SZ_N4     = 40032;                           // (NNODE+1)*4 padded
constexpr size_t OFF_SD    = OFF_SS  + SZ_N4;
constexpr size_t OFF_CNT   = OFF_SD  + SZ_N4;                 // histogram (zeroed)
constexpr size_t OFF_START = OFF_CNT + SZ_N4;                 // CSR offsets [NNODE+1]
constexpr size_t OFF_CUR   = OFF_START + SZ_N4;               // scatter cursors
constexpr size_t OFF_ESRC  = OFF_CUR + SZ_N4;                 // sorted src  [NEDGE]
constexpr size_t OFF_ESC   = OFF_ESRC + NEDGE * 4;            // sorted score[NEDGE]

// ---------- helpers ----------
__device__ __forceinline__ unsigned short f2bf(float f) {
  unsigned int u = __float_as_uint(f);
  u += 0x7FFFu + ((u >> 16) & 1u);
  return (unsigned short)(u >> 16);
}
__device__ __forceinline__ float bf2f(unsigned short b) {
  return __uint_as_float(((unsigned int)b) << 16);
}

typedef __attribute__((ext_vector_type(8))) short bf16x8;
typedef __attribute__((ext_vector_type(4))) float f32x4;

__device__ __forceinline__ void gl2lds16(const unsigned short* g, unsigned short* l) {
  __builtin_amdgcn_global_load_lds(
      (const __attribute__((address_space(1))) unsigned int*)g,
      (__attribute__((address_space(3))) unsigned int*)l, 16, 0, 0);
}

// ---------- 1. prep: W^T (bf16) + wa vectors (f32) ----------
__global__ __launch_bounds__(256) void k_prep(const float* __restrict__ W,
                                              const float* __restrict__ a_s,
                                              const float* __restrict__ a_d,
                                              unsigned short* __restrict__ wT,
                                              float* __restrict__ wa_s,
                                              float* __restrict__ wa_d) {
  int bid = blockIdx.x, tid = threadIdx.x;
  if (bid < 576) {                       // 24x24 tiles of 32x32 transpose
    __shared__ float tile[32][33];
    int tx0 = (bid % 24) * 32, ty0 = (bid / 24) * 32;
    int cx = tid & 31, cy = tid >> 5;    // cy 0..7
#pragma unroll
    for (int r = 0; r < 4; ++r)
      tile[cy + r * 8][cx] = W[(size_t)(ty0 + cy + r * 8) * HDIM + tx0 + cx];
    __syncthreads();
#pragma unroll
    for (int r = 0; r < 4; ++r)
      wT[(size_t)(tx0 + cy + r * 8) * HDIM + ty0 + cx] = f2bf(tile[cx][cy + r * 8]);
  } else {                               // wa rows: 192 blocks * 4 waves = 768 rows
    int lane = tid & 63, wid = tid >> 6;
    int row = (bid - 576) * 4 + wid;
    float ss = 0.f, sd = 0.f;
    for (int n = lane; n < HDIM; n += 64) {
      float w = W[(size_t)row * HDIM + n];
      ss += w * a_s[n];
      sd += w * a_d[n];
    }
#pragma unroll
    for (int off = 32; off; off >>= 1) {
      ss += __shfl_down(ss, off, 64);
      sd += __shfl_down(sd, off, 64);
    }
    if (lane == 0) { wa_s[row] = ss; wa_d[row] = sd; }
  }
}

// ---------- 2. fused: featbf = bf16(feat) ; s_src/s_dst = feat . wa ----------
__global__ __launch_bounds__(256) void k_convert_scores(const float* __restrict__ feat,
                                                        const float* __restrict__ wa_s,
                                                        const float* __restrict__ wa_d,
                                                        unsigned short* __restrict__ featbf,
                                                        float* __restrict__ s_s,
                                                        float* __restrict__ s_d) {
  int lane = threadIdx.x & 63, wid = threadIdx.x >> 6;
  int r = blockIdx.x * 4 + wid;
  if (r >= NNODE) return;
  const float4* fr = (const float4*)(feat + (size_t)r * HDIM);
  ushort4* ob = (ushort4*)(featbf + (size_t)r * HDIM);
  float ss = 0.f, sd = 0.f;
#pragma unroll
  for (int i = 0; i < 3; ++i) {
    int c = lane + i * 64;               // float4 chunk 0..191
    float4 v = fr[c];
    float4 vs = ((const float4*)wa_s)[c];
    float4 vd = ((const float4*)wa_d)[c];
    ss += v.x * vs.x + v.y * vs.y + v.z * vs.z + v.w * vs.w;
    sd += v.x * vd.x + v.y * vd.y + v.z * vd.z + v.w * vd.w;
    ushort4 o;
    o.x = f2bf(v.x); o.y = f2bf(v.y); o.z = f2bf(v.z); o.w = f2bf(v.w);
    ob[c] = o;
  }
#pragma unroll
  for (int off = 32; off; off >>= 1) {
    ss += __shfl_down(ss, off, 64);
    sd += __shfl_down(sd, off, 64);
  }
  if (lane == 0) { s_s[r] = ss; s_d[r] = sd; }
}

// ---------- 3. GEMM h = feat @ W  (A: M x K bf16, BT: N x K bf16) ----------
__global__ __launch_bounds__(256) void k_gemm(const unsigned short* __restrict__ A,
                                              const unsigned short* __restrict__ BT,
                                              unsigned short* __restrict__ Hout) {
  __shared__ __align__(16) unsigned short As[128 * 32];
  __shared__ __align__(16) unsigned short Bs[128 * 32];
  int tid = threadIdx.x, lane = tid & 63, wid = tid >> 6;
  int m0 = blockIdx.x * 128, n0 = blockIdx.y * 128;
  int wm = wid >> 1, wn = wid & 1;
  int q = lane >> 4, lr = lane & 15;

  f32x4 acc[4][4];
#pragma unroll
  for (int i = 0; i < 4; ++i)
#pragma unroll
    for (int j = 0; j < 4; ++j) acc[i][j] = 0.f;

  for (int kt = 0; kt < 24; ++kt) {
    int k0 = kt * 32;
#pragma unroll
    for (int t = 0; t < 2; ++t) {
      int c = wid * 128 + t * 64 + lane;
      int row = c >> 2, kk = (c & 3) << 3;
      int grow = m0 + row;
      grow = grow <= NNODE - 1 ? grow : NNODE - 1;
      gl2lds16(A + (size_t)grow * HDIM + k0 + kk, As + (size_t)wid * 1024 + t * 512);
      int nrow = n0 + row;
      gl2lds16(BT + (size_t)nrow * HDIM + k0 + kk, Bs + (size_t)wid * 1024 + t * 512);
    }
    __syncthreads();
    bf16x8 a[4], b[4];
#pragma unroll
    for (int i = 0; i < 4; ++i)
      a[i] = *(const bf16x8*)(As + (wm * 64 + i * 16 + lr) * 32 + q * 8);
#pragma unroll
    for (int j = 0; j < 4; ++j)
      b[j] = *(const bf16x8*)(Bs + (wn * 64 + j * 16 + lr) * 32 + q * 8);
#pragma unroll
    for (int i = 0; i < 4; ++i)
#pragma unroll
      for (int j = 0; j < 4; ++j)
        acc[i][j] = __builtin_amdgcn_mfma_f32_16x16x32_bf16(a[i], b[j], acc[i][j], 0, 0, 0);
    __syncthreads();
  }
#pragma unroll
  for (int i = 0; i < 4; ++i) {
    int mbase = m0 + wm * 64 + i * 16 + q * 4;
#pragma unroll
    for (int j = 0; j < 4; ++j) {
      int n = n0 + wn * 64 + j * 16 + lr;
#pragma unroll
      for (int rg = 0; rg < 4; ++rg) {
        int m = mbase + rg;
        if (m < NNODE) Hout[(size_t)m * HDIM + n] = f2bf(acc[i][j][rg]);
      }
    }
  }
}

// ---------- 4. histogram over dst ----------
__global__ __launch_bounds__(256) void k_hist(const int* __restrict__ ei,
                                              int* __restrict__ count) {
  int e = blockIdx.x * 256 + threadIdx.x;
  if (e >= NEDGE) return;
  atomicAdd(count + ei[NEDGE + e], 1);
}

// ---------- 5. exclusive scan (single block) ----------
__global__ __launch_bounds__(256) void k_scan(const int* __restrict__ count,
                                              int* __restrict__ start,
                                              int* __restrict__ cursor) {
  __shared__ int part[256];
  int tid = threadIdx.x;
  int base = tid * 40;                    // 40*256 = 10240 >= NNODE
  int loc[40];
  int s = 0;
#pragma unroll
  for (int i = 0; i < 40; ++i) {
    int idx = base + i;
    int c = (idx < NNODE) ? count[idx] : 0;
    loc[i] = s; s += c;
  }
  part[tid] = s;
  __syncthreads();
  for (int d = 1; d < 256; d <<= 1) {
    int t = (tid >= d) ? part[tid - d] : 0;
    __syncthreads();
    part[tid] += t;
    __syncthreads();
  }
  int excl = part[tid] - s;
#pragma unroll
  for (int i = 0; i < 40; ++i) {
    int idx = base + i;
    if (idx < NNODE) {
      int v = excl + loc[i];
      start[idx] = v;
      cursor[idx] = v;
    }
  }
  if (tid == 255) start[NNODE] = part[255];
}

// ---------- 6. scatter edges into CSR (src + leaky score) ----------
__global__ __launch_bounds__(256) void k_scatter(const int* __restrict__ ei,
                                                 const float* __restrict__ s_s,
                                                 const float* __restrict__ s_d,
                                                 int* __restrict__ cursor,
                                                 int* __restrict__ esrc,
                                                 float* __restrict__ escore) {
  int e = blockIdx.x * 256 + threadIdx.x;
  if (e >= NEDGE) return;
  int src = ei[e], dst = ei[NEDGE + e];
  float v = s_s[src] + s_d[dst];
  v = v > 0.f ? v : SLOPE * v;
  int pos = atomicAdd(cursor + dst, 1);
  esrc[pos] = src;
  escore[pos] = v;
}

// ---------- 7. aggregate per dst node + fused finalize ----------
__global__ __launch_bounds__(256) void k_aggregate(const int* __restrict__ start,
                                                   const int* __restrict__ esrc,
                                                   const float* __restrict__ escore,
                                                   const unsigned short* __restrict__ h,
                                                   const float* __restrict__ feat,
                                                   float* __restrict__ fo) {
  int n = blockIdx.x, t = threadIdx.x;
  int b = start[n], en = start[n + 1];
  float m = -3.4e38f;
  for (int e = b; e < en; ++e) m = fmaxf(m, escore[e]);
  float a0 = 0.f, a1 = 0.f, a2 = 0.f, den = 0.f;
  for (int e = b; e < en; ++e) {
    float ex = __expf(escore[e] - m);
    den += ex;
    const unsigned short* hr = h + (size_t)esrc[e] * HDIM;
    a0 += ex * bf2f(hr[t]);
    a1 += ex * bf2f(hr[t + 256]);
    a2 += ex * bf2f(hr[t + 512]);
  }
  float inv = 1.f / (den + 1e-16f);       // deg==0: acc=0 -> fo=feat (0*1e16==0)
  size_t o = (size_t)n * HDIM + t;
  fo[o]       = feat[o]       + a0 * inv;
  fo[o + 256] = feat[o + 256] + a1 * inv;
  fo[o + 512] = feat[o + 512] + a2 * inv;
}

// ---------- 8. gather: out[b,s,:]  (f32, 16B chunks) ----------
__global__ __launch_bounds__(256) void k_gather(const int* __restrict__ x,
                                                const float* __restrict__ orig,
                                                const float* __restrict__ nw,
                                                const float* __restrict__ soft,
                                                const float* __restrict__ fo,
                                                uint4* __restrict__ out) {
  int chunk = blockIdx.x * 256 + threadIdx.x;     // 192 chunks/row, 32768 rows
  int row = chunk / 192;
  int c4 = chunk - row * 192;
  int s = row & 511;
  const float* g;
  if (s < 8) {
    g = soft + (size_t)s * HDIM + c4 * 4;
  } else {
    int idx = x[row];
    if (idx < VOCAB) g = orig + (size_t)idx * HDIM + c4 * 4;
    else if (idx < VOCAB + NNODE) g = fo + (size_t)(idx - VOCAB) * HDIM + c4 * 4;
    else g = nw + (size_t)(NROWS - 1) * HDIM + c4 * 4;
  }
  out[chunk] = *(const uint4*)g;
}

// ---------- launch ----------
extern "C" void kernel_launch(void* const* d_in, const int* in_sizes, int n_in,
                              void* d_out, int out_size, void* d_ws, size_t ws_size,
                              hipStream_t stream) {
  const int* x    = (const int*)d_in[0];
  const int* ei   = (const int*)d_in[1];
  const float* og = (const float*)d_in[2];
  const float* nw = (const float*)d_in[3];
  const float* sp = (const float*)d_in[4];
  const float* W  = (const float*)d_in[5];
  const float* as = (const float*)d_in[6];
  const float* ad = (const float*)d_in[7];
  const float* feat = nw + HDIM;                  // new_weight rows 1..10002

  char* ws = (char*)d_ws;
  unsigned short* hbuf   = (unsigned short*)(ws + OFF_H);
  unsigned short* featbf = (unsigned short*)(ws + OFF_FB);
  float* fo              = (float*)(ws + OFF_FO);
  unsigned short* wT     = (unsigned short*)(ws + OFF_WT);
  float* wa_s            = (float*)(ws + OFF_WAS);
  float* wa_d            = (float*)(ws + OFF_WAD);
  float* s_s             = (float*)(ws + OFF_SS);
  float* s_d             = (float*)(ws + OFF_SD);
  int* count             = (int*)(ws + OFF_CNT);
  int* startArr          = (int*)(ws + OFF_START);
  int* cursor            = (int*)(ws + OFF_CUR);
  int* esrc              = (int*)(ws + OFF_ESRC);
  float* escore          = (float*)(ws + OFF_ESC);

  (void)hipMemsetAsync(count, 0, SZ_N4, stream);
  k_prep<<<768, 256, 0, stream>>>(W, as, ad, wT, wa_s, wa_d);
  k_convert_scores<<<(NNODE + 3) / 4, 256, 0, stream>>>(feat, wa_s, wa_d, featbf, s_s, s_d);
  k_gemm<<<dim3(79, 6), 256, 0, stream>>>(featbf, wT, hbuf);
  k_hist<<<(NEDGE + 255) / 256, 256, 0, stream>>>(ei, count);
  k_scan<<<1, 256, 0, stream>>>(count, startArr, cursor);
  k_scatter<<<(NEDGE + 255) / 256, 256, 0, stream>>>(ei, s_s, s_d, cursor, esrc, escore);
  k_aggregate<<<NNODE, 256, 0, stream>>>(startArr, esrc, escore, hbuf, feat, fo);
  k_gather<<<(32768 * 192) / 256, 256, 0, stream>>>(x, og, nw, sp, fo, (uint4*)d_out);
}